// Round 3
// baseline (1154.042 us; speedup 1.0000x reference)
//
#include <hip/hip_runtime.h>
#include <hip/hip_fp16.h>

#define NN 100000
#define NE 3200000
#define NG 1024
#define NP 100352            // NN padded to multiple of 256
#define NBUCK 391            // ceil(NN/256) buckets of 256 dst nodes
#define NBLK 256
#define CHUNK ((NE + NBLK - 1) / NBLK)
#define SPLIT_LOG2 2         // 4 blocks per bucket in agg_edge

// ---------- fp16 pack helpers ----------
static __device__ inline uint2 pack4(float a, float b, float c, float d) {
    __half2 lo = __floats2half2_rn(a, b);
    __half2 hi = __floats2half2_rn(c, d);
    uint2 u;
    u.x = *reinterpret_cast<unsigned int*>(&lo);
    u.y = *reinterpret_cast<unsigned int*>(&hi);
    return u;
}

// ---- k1: per-bucket edge histogram ----
__global__ void hist_buckets(const int* __restrict__ dst, int* __restrict__ bcnt) {
    __shared__ int sm[NBUCK];
    int tid = threadIdx.x;
    for (int i = tid; i < NBUCK; i += 256) sm[i] = 0;
    __syncthreads();
    int s = blockIdx.x * CHUNK, e = min(NE, s + CHUNK);
    for (int i = s + tid; i < e; i += 256) atomicAdd(&sm[dst[i] >> 8], 1);
    __syncthreads();
    for (int i = tid; i < NBUCK; i += 256)
        if (sm[i]) atomicAdd(&bcnt[i], sm[i]);
}

// ---- k2: exclusive scan of bucket counts ----
__global__ void scan_buckets(const int* __restrict__ bcnt, int* __restrict__ bbase) {
    __shared__ int tmp[512];
    int tid = threadIdx.x;
    int v = (tid < NBUCK) ? bcnt[tid] : 0;
    tmp[tid] = v;
    __syncthreads();
    for (int off = 1; off < 512; off <<= 1) {
        int t = (tid >= off) ? tmp[tid - off] : 0;
        __syncthreads();
        tmp[tid] += t;
        __syncthreads();
    }
    if (tid < NBUCK) bbase[tid] = tmp[tid] - v;
}

// ---- k3: partition edges into bucket regions, packed (dst&255)<<17 | src ----
__global__ void partition(const int* __restrict__ src, const int* __restrict__ dst,
                          const int* __restrict__ bbase, int* __restrict__ bfill,
                          int* __restrict__ part) {
    __shared__ int smh[NBUCK];
    __shared__ int smc[NBUCK];
    int tid = threadIdx.x;
    for (int i = tid; i < NBUCK; i += 256) smh[i] = 0;
    __syncthreads();
    int s = blockIdx.x * CHUNK, e = min(NE, s + CHUNK);
    for (int i = s + tid; i < e; i += 256) atomicAdd(&smh[dst[i] >> 8], 1);
    __syncthreads();
    for (int i = tid; i < NBUCK; i += 256) {
        int c = smh[i];
        smc[i] = c ? (bbase[i] + atomicAdd(&bfill[i], c)) : 0;
    }
    __syncthreads();
    for (int i = s + tid; i < e; i += 256) {
        int d = dst[i];
        int b = d >> 8;
        int p = atomicAdd(&smc[b], 1);
        part[p] = src[i] | ((d & 255) << 17);
    }
}

// ---- k4: per-bucket degree histogram -> dis (replaces CSR build; srcs no longer needed) ----
__global__ void deg_dis(const int* __restrict__ part, const int* __restrict__ bbase,
                        const int* __restrict__ bcnt, float* __restrict__ dis) {
    __shared__ int smc[256];
    int b = blockIdx.x, tid = threadIdx.x;
    smc[tid] = 0;
    __syncthreads();
    int base = bbase[b], m = bcnt[b];
    for (int i = base + tid; i < base + m; i += 256) atomicAdd(&smc[part[i] >> 17], 1);
    __syncthreads();
    int n = b * 256 + tid;
    if (n < NN) dis[n] = rsqrtf((float)smc[tid] + 1.0f);
}

// ---- embed one-hot + transform by Wg0, premultiply dis, fp16 out ----
__global__ void embed_tf0(const int* __restrict__ types, const int* __restrict__ pos,
                          const float* __restrict__ W1, const float* __restrict__ b1,
                          const float* __restrict__ W2, const float* __restrict__ b2,
                          const float* __restrict__ Wg0, const float* __restrict__ dis,
                          uint2* __restrict__ hs) {
    __shared__ float sW[32 * 16];
    int tid = threadIdx.x;
    sW[tid] = Wg0[tid];
    sW[tid + 256] = Wg0[tid + 256];
    __syncthreads();
    int n = blockIdx.x * 256 + tid;
    if (n >= NN) return;
    int ty = types[n], pp = pos[n];
    float z[32];
#pragma unroll
    for (int j = 0; j < 16; j++) z[j] = W1[ty * 16 + j] + b1[j];
#pragma unroll
    for (int j = 0; j < 16; j++) z[16 + j] = W2[pp * 16 + j] + b2[j];
    float dn = dis[n];
    uint2 o[4];
#pragma unroll
    for (int q = 0; q < 4; q++) {
        float hv[4];
#pragma unroll
        for (int m = 0; m < 4; m++) {
            float a = 0.0f;
#pragma unroll
            for (int k = 0; k < 32; k++) a += z[k] * sW[k * 16 + q * 4 + m];
            hv[m] = a * dn;
        }
        o[q] = pack4(hv[0], hv[1], hv[2], hv[3]);
    }
#pragma unroll
    for (int q = 0; q < 4; q++) hs[(size_t)n * 4 + q] = o[q];
}

// ---- edge-parallel aggregation: one lane per edge, LDS fp32 accumulators ----
// acc[dst_local][16] (padded to 17) ; merge to global zagg via coalesced atomics.
// Every edge is independent -> deep MLP, no per-lane dependent chain.
static __device__ inline void acc16(float* __restrict__ ap, uint4 a, uint4 b) {
    const __half2* h = reinterpret_cast<const __half2*>(&a);
    const __half2* g = reinterpret_cast<const __half2*>(&b);
    float2 f0 = __half22float2(h[0]), f1 = __half22float2(h[1]);
    float2 f2 = __half22float2(h[2]), f3 = __half22float2(h[3]);
    float2 f4 = __half22float2(g[0]), f5 = __half22float2(g[1]);
    float2 f6 = __half22float2(g[2]), f7 = __half22float2(g[3]);
    atomicAdd(ap + 0, f0.x);  atomicAdd(ap + 1, f0.y);
    atomicAdd(ap + 2, f1.x);  atomicAdd(ap + 3, f1.y);
    atomicAdd(ap + 4, f2.x);  atomicAdd(ap + 5, f2.y);
    atomicAdd(ap + 6, f3.x);  atomicAdd(ap + 7, f3.y);
    atomicAdd(ap + 8, f4.x);  atomicAdd(ap + 9, f4.y);
    atomicAdd(ap + 10, f5.x); atomicAdd(ap + 11, f5.y);
    atomicAdd(ap + 12, f6.x); atomicAdd(ap + 13, f6.y);
    atomicAdd(ap + 14, f7.x); atomicAdd(ap + 15, f7.y);
}

__global__ __launch_bounds__(256, 4) void agg_edge(
        const uint2* __restrict__ hs, const int* __restrict__ part,
        const int* __restrict__ bbase, const int* __restrict__ bcnt,
        float* __restrict__ zagg) {
    __shared__ float acc[256 * 17];
    int tid = threadIdx.x;
    int b = blockIdx.x >> SPLIT_LOG2;
    int s = blockIdx.x & ((1 << SPLIT_LOG2) - 1);
    for (int i = tid; i < 256 * 17; i += 256) acc[i] = 0.f;
    __syncthreads();
    int base = bbase[b], m = bcnt[b];
    int s0 = (int)(((long long)m * s) >> SPLIT_LOG2);
    int s1 = (int)(((long long)m * (s + 1)) >> SPLIT_LOG2);
    int i = base + s0 + tid;
    int end = base + s1;

    // 4x unrolled main: 4 part loads, then 8 gathers, then 64 LDS atomics.
    for (; i + 768 < end; i += 1024) {
        int p0 = part[i];
        int p1 = part[i + 256];
        int p2 = part[i + 512];
        int p3 = part[i + 768];
        const uint4* q0 = (const uint4*)(hs + (size_t)(p0 & 0x1FFFF) * 4);
        const uint4* q1 = (const uint4*)(hs + (size_t)(p1 & 0x1FFFF) * 4);
        const uint4* q2 = (const uint4*)(hs + (size_t)(p2 & 0x1FFFF) * 4);
        const uint4* q3 = (const uint4*)(hs + (size_t)(p3 & 0x1FFFF) * 4);
        uint4 a0 = q0[0], b0 = q0[1];
        uint4 a1 = q1[0], b1 = q1[1];
        uint4 a2 = q2[0], b2 = q2[1];
        uint4 a3 = q3[0], b3 = q3[1];
        acc16(acc + (p0 >> 17) * 17, a0, b0);
        acc16(acc + (p1 >> 17) * 17, a1, b1);
        acc16(acc + (p2 >> 17) * 17, a2, b2);
        acc16(acc + (p3 >> 17) * 17, a3, b3);
    }
    for (; i < end; i += 256) {
        int p = part[i];
        const uint4* q = (const uint4*)(hs + (size_t)(p & 0x1FFFF) * 4);
        uint4 a = q[0], bb = q[1];
        acc16(acc + (p >> 17) * 17, a, bb);
    }
    __syncthreads();

    // coalesced merge into zagg[b*4096 .. +4096)
    float* zb = zagg + (size_t)b * 4096;
    for (int f = tid; f < 4096; f += 256) {
        float v = acc[(f >> 4) * 17 + (f & 15)];
        atomicAdd(zb + f, v);
    }
}

// ---- node-parallel: self loop + bias (+relu) + 16x16 transform + fp16 repack ----
// Also re-zeroes zagg behind itself for the next layer (skip when FUSE_POOL).
template <int RELU, int FUSE_POOL>
__global__ void tf_node(float* __restrict__ zagg, const uint2* __restrict__ hs,
                        const float* __restrict__ dis, const float* __restrict__ bias,
                        const float* __restrict__ Wn, uint2* __restrict__ hs_out,
                        const int* __restrict__ batch, float* __restrict__ pool,
                        int* __restrict__ gcnt) {
    __shared__ float sW[256];
    int tid = threadIdx.x;
    if (!FUSE_POOL) {
        sW[tid] = Wn[tid];
        __syncthreads();
    }
    int n = blockIdx.x * 256 + tid;
    if (n >= NN) return;
    float4* zp = (float4*)(zagg + (size_t)n * 16);
    float4 z0 = zp[0], z1 = zp[1], z2 = zp[2], z3 = zp[3];
    const uint4* hp = (const uint4*)(hs + (size_t)n * 4);
    uint4 ha = hp[0], hb = hp[1];
    if (!FUSE_POOL) {
        float4 zero4 = make_float4(0.f, 0.f, 0.f, 0.f);
        zp[0] = zero4; zp[1] = zero4; zp[2] = zero4; zp[3] = zero4;
    }
    float dn = dis[n];
    const __half2* h = reinterpret_cast<const __half2*>(&ha);
    const __half2* g = reinterpret_cast<const __half2*>(&hb);
    float2 s0 = __half22float2(h[0]), s1 = __half22float2(h[1]);
    float2 s2 = __half22float2(h[2]), s3 = __half22float2(h[3]);
    float2 s4 = __half22float2(g[0]), s5 = __half22float2(g[1]);
    float2 s6 = __half22float2(g[2]), s7 = __half22float2(g[3]);
    float z[16];
    z[0] = z0.x + s0.x;  z[1] = z0.y + s0.y;  z[2] = z0.z + s1.x;  z[3] = z0.w + s1.y;
    z[4] = z1.x + s2.x;  z[5] = z1.y + s2.y;  z[6] = z1.z + s3.x;  z[7] = z1.w + s3.y;
    z[8] = z2.x + s4.x;  z[9] = z2.y + s4.y;  z[10] = z2.z + s5.x; z[11] = z2.w + s5.y;
    z[12] = z3.x + s6.x; z[13] = z3.y + s6.y; z[14] = z3.z + s7.x; z[15] = z3.w + s7.y;
#pragma unroll
    for (int j = 0; j < 16; j++) {
        z[j] = fmaf(z[j], dn, bias[j]);
        if (RELU) z[j] = fmaxf(z[j], 0.f);
    }
    if (FUSE_POOL) {
        float sacc = 0.f;
#pragma unroll
        for (int j = 0; j < 16; j++) sacc += z[j] * Wn[j];
        int gg = batch[n];
        atomicAdd(&pool[gg], sacc);
        atomicAdd(&gcnt[gg], 1);
    } else {
        uint2 o[4];
#pragma unroll
        for (int q = 0; q < 4; q++) {
            float hv[4];
#pragma unroll
            for (int mm = 0; mm < 4; mm++) {
                float a = 0.f;
#pragma unroll
                for (int k = 0; k < 16; k++) a += z[k] * sW[k * 16 + q * 4 + mm];
                hv[mm] = a * dn;
            }
            o[q] = pack4(hv[0], hv[1], hv[2], hv[3]);
        }
        uint2* op = hs_out + (size_t)n * 4;
#pragma unroll
        for (int q = 0; q < 4; q++) op[q] = o[q];
    }
}

__global__ void finalize(const float* __restrict__ pool, const int* __restrict__ gcnt,
                         const float* __restrict__ bo, float* __restrict__ out) {
    int g = blockIdx.x * 256 + threadIdx.x;
    if (g < NG) {
        float c = fmaxf((float)gcnt[g], 1.0f);
        out[g] = pool[g] / c + bo[0];
    }
}

extern "C" void kernel_launch(void* const* d_in, const int* in_sizes, int n_in,
                              void* d_out, int out_size, void* d_ws, size_t ws_size,
                              hipStream_t stream) {
    const int*   types = (const int*)d_in[0];
    const int*   pos   = (const int*)d_in[1];
    const int*   ei    = (const int*)d_in[2];   // [2, E]: src then dst
    const int*   batch = (const int*)d_in[3];
    const float* W1  = (const float*)d_in[4];
    const float* b1  = (const float*)d_in[5];
    const float* W2  = (const float*)d_in[6];
    const float* b2  = (const float*)d_in[7];
    const float* Wg0 = (const float*)d_in[8];
    const float* bg0 = (const float*)d_in[9];
    const float* Wg1 = (const float*)d_in[10];
    const float* bg1 = (const float*)d_in[11];
    const float* Wg2 = (const float*)d_in[12];
    const float* bg2 = (const float*)d_in[13];
    const float* Wo  = (const float*)d_in[14];
    const float* bo  = (const float*)d_in[15];
    float* out = (float*)d_out;

    const int* esrc = ei;
    const int* edst = ei + NE;

    // ---- workspace layout (ints), all 16B-aligned ----
    int*   bcnt  = (int*)d_ws;                   // 512  (zeroed)
    int*   bfill = bcnt + 512;                   // 512  (zeroed)
    float* pool  = (float*)(bfill + 512);        // 1024 (zeroed)
    int*   gcnt  = (int*)(pool + NG);            // 1024 (zeroed)
    int*   bbase = gcnt + NG;                    // 512
    float* dis   = (float*)(bbase + 512);        // NP floats
    int*   part  = (int*)(dis + NP);             // NE  (persists across layers)
    float* zagg  = (float*)(part + NE);          // NP*16 floats (fp32 edge sums)
    uint2* hsA   = (uint2*)(zagg + (size_t)NP * 16);  // NP*4 uint2 = 3.2 MB
    uint2* hsB   = (uint2*)((int*)hsA + NP * 8);      // 3.2 MB
    (void)ws_size; (void)n_in; (void)in_sizes; (void)out_size;

    hipMemsetAsync(d_ws, 0, (size_t)(1024 + 2 * NG) * sizeof(int), stream);
    hipMemsetAsync(zagg, 0, (size_t)NP * 16 * sizeof(float), stream);

    const int NB256 = (NN + 255) / 256;          // 391

    hist_buckets<<<NBLK, 256, 0, stream>>>(edst, bcnt);
    scan_buckets<<<1, 512, 0, stream>>>(bcnt, bbase);
    partition<<<NBLK, 256, 0, stream>>>(esrc, edst, bbase, bfill, part);
    deg_dis<<<NBUCK, 256, 0, stream>>>(part, bbase, bcnt, dis);

    // layer 0 input: hs0 = (z0 @ Wg0) * dis  (fp16)
    embed_tf0<<<NB256, 256, 0, stream>>>(types, pos, W1, b1, W2, b2, Wg0, dis, hsA);

    // layer 0: edge-parallel agg -> zagg ; node pass: +self +bg0, relu, @Wg1 -> hsB
    agg_edge<<<NBUCK << SPLIT_LOG2, 256, 0, stream>>>(hsA, part, bbase, bcnt, zagg);
    tf_node<1, 0><<<NB256, 256, 0, stream>>>(zagg, hsA, dis, bg0, Wg1, hsB,
                                             batch, pool, gcnt);
    // layer 1
    agg_edge<<<NBUCK << SPLIT_LOG2, 256, 0, stream>>>(hsB, part, bbase, bcnt, zagg);
    tf_node<1, 0><<<NB256, 256, 0, stream>>>(zagg, hsB, dis, bg1, Wg2, hsA,
                                             batch, pool, gcnt);
    // layer 2: agg + (no relu) + Wo dot + pool
    agg_edge<<<NBUCK << SPLIT_LOG2, 256, 0, stream>>>(hsA, part, bbase, bcnt, zagg);
    tf_node<0, 1><<<NB256, 256, 0, stream>>>(zagg, hsA, dis, bg2, Wo, hsB /*unused*/,
                                             batch, pool, gcnt);

    finalize<<<(NG + 255) / 256, 256, 0, stream>>>(pool, gcnt, bo, out);
}